// Round 7
// baseline (1993.182 us; speedup 1.0000x reference)
//
#include <hip/hip_runtime.h>
#include <hip/hip_bf16.h>
#include <stdint.h>

// Problem constants
#define NN 20000      // nodes
#define NE 640000     // edges
#define HID 512
#define MID 4352
#define VOC 8192

typedef __attribute__((ext_vector_type(4))) float f32x4;
typedef __attribute__((ext_vector_type(8))) short bf16x8;

__device__ __forceinline__ unsigned short f2bf(float f) {
  unsigned int u = __float_as_uint(f);
  u += 0x7fffu + ((u >> 16) & 1u);   // round-to-nearest-even
  return (unsigned short)(u >> 16);
}

// ---------------- detect edge_index storage width ----------------
__global__ void k_detect64(const int* __restrict__ ei32, int* __restrict__ flag) {
  __shared__ int any_nz;
  if (threadIdx.x == 0) any_nz = 0;
  __syncthreads();
  int v = ei32[2 * threadIdx.x + 1];
  if (v != 0) atomicOr(&any_nz, 1);
  __syncthreads();
  if (threadIdx.x == 0) *flag = (any_nz == 0) ? 1 : 0;  // 1 => int64 layout
}

__global__ void k_zero_i32(int* __restrict__ p, int n) {
  int i = blockIdx.x * blockDim.x + threadIdx.x;
  if (i < n) p[i] = 0;
}

__global__ void k_count(const int* __restrict__ ei, const int* __restrict__ flag,
                        int* __restrict__ deg) {
  int e = blockIdx.x * blockDim.x + threadIdx.x;
  if (e >= NE) return;
  int is64 = *flag;
  int d = is64 ? ei[2 * (NE + e)] : ei[NE + e];
  if ((unsigned)d >= NN) return;
  atomicAdd(&deg[d], 1);
}

__global__ __launch_bounds__(1024)
void k_scan(const int* __restrict__ deg, int* __restrict__ offs, int* __restrict__ cursor) {
  __shared__ int part[1024];
  const int t = threadIdx.x;
  const int CH = (NN + 1023) / 1024;  // 20
  const int base = t * CH;
  int s = 0;
  for (int i = 0; i < CH; ++i) { int idx = base + i; if (idx < NN) s += deg[idx]; }
  part[t] = s;
  __syncthreads();
  for (int off = 1; off < 1024; off <<= 1) {
    int v = (t >= off) ? part[t - off] : 0;
    __syncthreads();
    part[t] += v;
    __syncthreads();
  }
  int run = (t == 0) ? 0 : part[t - 1];  // exclusive prefix
  for (int i = 0; i < CH; ++i) {
    int idx = base + i;
    if (idx < NN) { offs[idx] = run; cursor[idx] = run; run += deg[idx]; }
  }
}

__global__ void k_fill(const int* __restrict__ ei, const int* __restrict__ flag,
                       int* __restrict__ cursor, int* __restrict__ csr) {
  int e = blockIdx.x * blockDim.x + threadIdx.x;
  if (e >= NE) return;
  int is64 = *flag;
  int s, d;
  if (is64) { s = ei[2 * e]; d = ei[2 * (NE + e)]; }
  else      { s = ei[e];     d = ei[NE + e]; }
  if ((unsigned)s >= NN || (unsigned)d >= NN) return;
  int pos = atomicAdd(&cursor[d], 1);
  csr[pos] = s;
}

// ---------------- fused gather + (1+eps)*x + bf16 convert ----------------
__global__ __launch_bounds__(256)
void k_gather_bf16(const float4* __restrict__ x4, const int* __restrict__ offs,
                   const int* __restrict__ deg, const int* __restrict__ csr,
                   uint4* __restrict__ hb4) {
  const int wid = blockIdx.x * (blockDim.x >> 6) + (threadIdx.x >> 6);
  if (wid >= NN) return;
  const int lane = threadIdx.x & 63;
  const long long rb0 = (long long)wid * 128 + lane * 2;
  float4 a0 = x4[rb0];
  float4 a1 = x4[rb0 + 1];
  const int beg = offs[wid];
  const int dc  = deg[wid];
  for (int j = 0; j < dc; ++j) {
    int s = csr[beg + j];
    long long rb = (long long)s * 128 + lane * 2;
    float4 v0 = x4[rb];
    float4 v1 = x4[rb + 1];
    a0.x += v0.x; a0.y += v0.y; a0.z += v0.z; a0.w += v0.w;
    a1.x += v1.x; a1.y += v1.y; a1.z += v1.z; a1.w += v1.w;
  }
  uint4 o;
  o.x = (unsigned)f2bf(a0.x) | ((unsigned)f2bf(a0.y) << 16);
  o.y = (unsigned)f2bf(a0.z) | ((unsigned)f2bf(a0.w) << 16);
  o.z = (unsigned)f2bf(a1.x) | ((unsigned)f2bf(a1.y) << 16);
  o.w = (unsigned)f2bf(a1.z) | ((unsigned)f2bf(a1.w) << 16);
  hb4[(long long)wid * 64 + lane] = o;
}

__global__ void k_f32_to_bf16(const float4* __restrict__ src, uint2* __restrict__ dst, int n4) {
  int i = blockIdx.x * blockDim.x + threadIdx.x;
  int stride = gridDim.x * blockDim.x;
  for (; i < n4; i += stride) {
    float4 v = src[i];
    uint2 o;
    o.x = (unsigned)f2bf(v.x) | ((unsigned)f2bf(v.y) << 16);
    o.y = (unsigned)f2bf(v.z) | ((unsigned)f2bf(v.w) << 16);
    dst[i] = o;
  }
}

// =================== 256x256 pipelined 8-phase bf16 GEMM, BK=32 ===================
// C[M,N] = A[M,K] * B[N,K]^T + bias.  512 thr = 8 waves (2Mx4N), per-wave 128x64.
// K-tiles of 32; 2 tiles (E->buf0, O->buf1) per 8-phase iteration.
// Reads for phase p+1 issue BEFORE MFMA of phase p (ds_read || MFMA overlap).
// SAFETY INVARIANT (R6 fix): counted vmcnt ALWAYS sits immediately before a
// barrier; LDS is read only after a {vmcnt covering the producing loads ->
// s_barrier} pair (vmcnt is per-wave; the barrier collectivizes it). A tile's
// A-reads span BOTH halves (wr split) -> stage both A halves in one phase,
// both B halves in the next. Waits: end-P2 vmcnt(2), end-P3 vmcnt(0),
// end-P6 vmcnt(2), end-P7 vmcnt(0).

#define SBAR  __builtin_amdgcn_s_barrier()
#define VMC(n) asm volatile("s_waitcnt vmcnt(" #n ")" ::: "memory")
#define FENCE asm volatile("" ::: "memory")
#define PRIO1 __builtin_amdgcn_s_setprio(1)
#define PRIO0 __builtin_amdgcn_s_setprio(0)

// read A half (4 frags of 16 rows) from byte base + qm*4096
#define RDA(DST, base, qm) { \
  DST[0] = *(const bf16x8*)((base) + (qm) * 4096);        \
  DST[1] = *(const bf16x8*)((base) + (qm) * 4096 + 1024); \
  DST[2] = *(const bf16x8*)((base) + (qm) * 4096 + 2048); \
  DST[3] = *(const bf16x8*)((base) + (qm) * 4096 + 3072); }

// read B half (2 frags) from byte base + qn*2048
#define RDB(DST, base, qn) { \
  DST[0] = *(const bf16x8*)((base) + (qn) * 2048);        \
  DST[1] = *(const bf16x8*)((base) + (qn) * 2048 + 1024); }

#define QUAD(AF, qm, BF, qn) \
  _Pragma("unroll") for (int m_ = 0; m_ < 4; ++m_) \
    _Pragma("unroll") for (int n_ = 0; n_ < 2; ++n_) \
      acc[(qm) * 4 + m_][(qn) * 2 + n_] = __builtin_amdgcn_mfma_f32_16x16x32_bf16( \
          AF[m_], BF[n_], acc[(qm) * 4 + m_][(qn) * 2 + n_], 0, 0, 0);

// stage one 8KB half (1 gload_lds / thread): A rows clamped for M-tail
#define STA(buf, h, kt) { \
  int gr_ = aRow0 + (h) * 128 + sRow; if (gr_ > Mm1) gr_ = Mm1; \
  __builtin_amdgcn_global_load_lds( \
    (const __attribute__((address_space(1))) void*)(A + (long long)gr_ * K + (kt) * 32 + sCol), \
    (__attribute__((address_space(3))) void*)(lds + (buf) * 32768 + (h) * 8192 + w * 1024), \
    16, 0, 0); }

#define STB(buf, h, kt) { \
  int gr_ = bRow0 + (h) * 128 + sRow; \
  __builtin_amdgcn_global_load_lds( \
    (const __attribute__((address_space(1))) void*)(B + (long long)gr_ * K + (kt) * 32 + sCol), \
    (__attribute__((address_space(3))) void*)(lds + (buf) * 32768 + 16384 + (h) * 8192 + w * 1024), \
    16, 0, 0); }

template<bool OUT_BF16>
__global__ __launch_bounds__(512, 2)
void k_gemm256p(const unsigned short* __restrict__ A,   // [M,K] bf16
                const unsigned short* __restrict__ B,   // [N,K] bf16
                const float* __restrict__ bias,         // [N]
                void* __restrict__ C,                   // [M,N] f32 or bf16
                int M, int N, int K)
{
  __shared__ __align__(16) char lds[65536];   // 2 bufs x (A 16KB + B 16KB)

  const int tid  = threadIdx.x;
  const int lane = tid & 63;
  const int w    = tid >> 6;       // 0..7
  const int wr   = w >> 2;         // 0..1  (M)
  const int wc   = w & 3;          // 0..3  (N)

  // grid mapping: bn-chunk per XCD if possible, else m204 bijective swizzle
  const int nwg  = gridDim.x * gridDim.y;
  const int orig = blockIdx.y * gridDim.x + blockIdx.x;
  int bn, bm;
  if ((gridDim.x & 7) == 0 && (nwg & 7) == 0) {
    const int xcd = orig & 7;
    const int j   = orig >> 3;
    const int chunk = gridDim.x >> 3;
    bn = xcd * chunk + (j % chunk);
    bm = j / chunk;
  } else {
    const int q = nwg >> 3, r = nwg & 7;
    const int xcd = orig & 7, land = orig >> 3;
    const int nid = (xcd < r ? xcd * (q + 1) : r * (q + 1) + (xcd - r) * q) + land;
    bn = nid % gridDim.x;
    bm = nid / gridDim.x;
  }

  const int lm = lane & 15;
  const int lk = lane >> 4;                 // 0..3
  const int aRow0 = bm * 256;
  const int bRow0 = bn * 256;
  const int Mm1 = M - 1;
  const int sRow = tid >> 2;                // 0..127 staging row within half
  const int sCol = (tid & 3) * 8;           // staging k-col (elems)

  // LDS read bases (bytes)
  const char* aRE = lds + (wr * 128 + lm) * 64 + lk * 16;          // buf0 A
  const char* aRO = aRE + 32768;                                   // buf1 A
  const char* bRE = lds + 16384 + (wc * 64 + lm) * 64 + lk * 16;   // buf0 B
  const char* bRO = bRE + 32768;                                   // buf1 B

  f32x4 acc[8][4] = {};
  bf16x8 aF0[4], aF1[4], bG0[2], bG1[2];

  const int nkt = K >> 5;            // K/32 tiles (even for K=512/4352)
  const int nit = nkt >> 1;

  // prologue: stage tile0 fully, drain globally, read its A0
  STA(0, 0, 0); STA(0, 1, 0); STB(0, 0, 0); STB(0, 1, 0);
  VMC(0);
  SBAR;
  RDA(aF0, aRE, 0);

  for (int i = 0; i < nit; ++i) {
    const int ktO = 2 * i + 1;
    int ktE2 = 2 * i + 2; if (ktE2 >= nkt) ktE2 = nkt - 1;  // junk on last iter (unused)
    // P0: stage A(O) both halves; read B0E,B1E; mfma qE(0,0)
    STA(1, 0, ktO); STA(1, 1, ktO);
    RDB(bG0, bRE, 0); RDB(bG1, bRE, 1);
    FENCE; PRIO1; QUAD(aF0, 0, bG0, 0); PRIO0; SBAR;
    // P1: stage B(O) both halves; read A1E; mfma qE(0,1)
    STB(1, 0, ktO); STB(1, 1, ktO);
    RDA(aF1, aRE, 1);
    FENCE; PRIO1; QUAD(aF0, 0, bG1, 1); PRIO0; SBAR;
    // P2: mfma qE(1,1); drain A(O) stages before barrier
    FENCE; PRIO1; QUAD(aF1, 1, bG1, 1); PRIO0; VMC(2); SBAR;
    // P3: read A0(O); mfma qE(1,0); drain B(O) stages before barrier
    RDA(aF0, aRO, 0);
    FENCE; PRIO1; QUAD(aF1, 1, bG0, 0); PRIO0; VMC(0); SBAR;
    // P4: stage A(E') both halves; read B0O,B1O; mfma qO(0,0)
    STA(0, 0, ktE2); STA(0, 1, ktE2);
    RDB(bG0, bRO, 0); RDB(bG1, bRO, 1);
    FENCE; PRIO1; QUAD(aF0, 0, bG0, 0); PRIO0; SBAR;
    // P5: stage B(E') both halves; read A1O; mfma qO(0,1)
    STB(0, 0, ktE2); STB(0, 1, ktE2);
    RDA(aF1, aRO, 1);
    FENCE; PRIO1; QUAD(aF0, 0, bG1, 1); PRIO0; SBAR;
    // P6: mfma qO(1,1); drain A(E') stages before barrier
    FENCE; PRIO1; QUAD(aF1, 1, bG1, 1); PRIO0; VMC(2); SBAR;
    // P7: read A0(E'); mfma qO(1,0); drain B(E') stages before barrier
    RDA(aF0, aRE, 0);
    FENCE; PRIO1; QUAD(aF1, 1, bG0, 0); PRIO0; VMC(0); SBAR;
  }

  // epilogue: C[row, col] = acc + bias
#pragma unroll
  for (int jn = 0; jn < 4; ++jn) {
    const int col = bn * 256 + wc * 64 + jn * 16 + lm;
    const float bv = bias[col];
#pragma unroll
    for (int im = 0; im < 8; ++im) {
      const int row0 = bm * 256 + wr * 128 + im * 16 + lk * 4;
#pragma unroll
      for (int jj = 0; jj < 4; ++jj) {
        const int row = row0 + jj;
        if (row < M) {
          const float v = acc[im][jn][jj] + bv;
          if (OUT_BF16)
            __builtin_nontemporal_store(f2bf(v), &((unsigned short*)C)[(long long)row * N + col]);
          else
            __builtin_nontemporal_store(v, &((float*)C)[(long long)row * N + col]);
        }
      }
    }
  }
}

extern "C" void kernel_launch(void* const* d_in, const int* in_sizes, int n_in,
                              void* d_out, int out_size, void* d_ws, size_t ws_size,
                              hipStream_t stream) {
  const float* x  = (const float*)d_in[0];
  const int*   ei = (const int*)d_in[1];      // int32 or int64 — detected on device
  const float* W1 = (const float*)d_in[2];
  const float* b1 = (const float*)d_in[3];
  const float* W2 = (const float*)d_in[4];
  const float* b2 = (const float*)d_in[5];
  float* out = (float*)d_out;
  char* ws = (char*)d_ws;

  // workspace layout (bytes, 16B-aligned)
  int* flag            = (int*)(ws + 0);                 // 256
  int* deg             = (int*)(ws + 256);               // 80,000
  int* offs            = (int*)(ws + 80256);             // 80,000
  int* cursor          = (int*)(ws + 160256);            // 80,000
  int* csr             = (int*)(ws + 240256);            // 2,560,000
  unsigned short* hb   = (unsigned short*)(ws + 2800256);   // 20,480,000
  unsigned short* w1b  = (unsigned short*)(ws + 23280256);  //  4,456,448
  unsigned short* w2b  = (unsigned short*)(ws + 27736704);  // 71,303,168
  const size_t h1_off  = 99039872;
  if (ws_size < h1_off + (size_t)256 * MID * 2) return;
  unsigned short* h1b  = (unsigned short*)(ws + h1_off);

  long long rem = (long long)ws_size - (long long)h1_off;
  int max_rows = (int)(rem / ((long long)MID * 2));
  max_rows = (max_rows / 256) * 256;
  if (max_rows > 20224) max_rows = 20224;

  // 0) detect edge_index width
  k_detect64<<<1, 256, 0, stream>>>(ei, flag);

  // 1) CSR build
  k_zero_i32<<<(NN + 255) / 256, 256, 0, stream>>>(deg, NN);
  k_count<<<(NE + 255) / 256, 256, 0, stream>>>(ei, flag, deg);
  k_scan<<<1, 1024, 0, stream>>>(deg, offs, cursor);
  k_fill<<<(NE + 255) / 256, 256, 0, stream>>>(ei, flag, cursor, csr);

  // 2) fused gather + bf16 convert: hb = bf16(x + sum_{j->i} x_j)
  k_gather_bf16<<<(NN + 3) / 4, 256, 0, stream>>>((const float4*)x, offs, deg, csr,
                                                  (uint4*)hb);

  // 3) weight conversions to bf16
  k_f32_to_bf16<<<1024, 256, 0, stream>>>((const float4*)W1, (uint2*)w1b, MID * HID / 4);
  k_f32_to_bf16<<<2048, 256, 0, stream>>>((const float4*)W2, (uint2*)w2b, VOC * MID / 4);

  // 4+5) chunked GEMM1 -> GEMM2 over M (usually a single chunk)
  for (int r0 = 0; r0 < NN; r0 += max_rows) {
    int mrows = (NN - r0 < max_rows) ? (NN - r0) : max_rows;
    dim3 g1(MID / 256, (mrows + 255) / 256);
    k_gemm256p<true><<<g1, 512, 0, stream>>>(hb + (size_t)r0 * HID, w1b, b1,
                                             (void*)h1b, mrows, MID, HID);
    dim3 g2(VOC / 256, (mrows + 255) / 256);
    k_gemm256p<false><<<g2, 512, 0, stream>>>(h1b, w2b, b2,
                                              (void*)(out + (size_t)r0 * VOC), mrows, VOC, MID);
  }
}

// Round 8
// 1765.468 us; speedup vs baseline: 1.1290x; 1.1290x over previous
//
#include <hip/hip_runtime.h>
#include <hip/hip_bf16.h>
#include <stdint.h>

// Problem constants
#define NN 20000      // nodes
#define NE 640000     // edges
#define HID 512
#define MID 4352
#define VOC 8192

typedef __attribute__((ext_vector_type(4))) float f32x4;
typedef __attribute__((ext_vector_type(8))) short bf16x8;

__device__ __forceinline__ unsigned short f2bf(float f) {
  unsigned int u = __float_as_uint(f);
  u += 0x7fffu + ((u >> 16) & 1u);   // round-to-nearest-even
  return (unsigned short)(u >> 16);
}

// ---------------- detect edge_index storage width ----------------
__global__ void k_detect64(const int* __restrict__ ei32, int* __restrict__ flag) {
  __shared__ int any_nz;
  if (threadIdx.x == 0) any_nz = 0;
  __syncthreads();
  int v = ei32[2 * threadIdx.x + 1];
  if (v != 0) atomicOr(&any_nz, 1);
  __syncthreads();
  if (threadIdx.x == 0) *flag = (any_nz == 0) ? 1 : 0;  // 1 => int64 layout
}

__global__ void k_zero_i32(int* __restrict__ p, int n) {
  int i = blockIdx.x * blockDim.x + threadIdx.x;
  if (i < n) p[i] = 0;
}

__global__ void k_count(const int* __restrict__ ei, const int* __restrict__ flag,
                        int* __restrict__ deg) {
  int e = blockIdx.x * blockDim.x + threadIdx.x;
  if (e >= NE) return;
  int is64 = *flag;
  int d = is64 ? ei[2 * (NE + e)] : ei[NE + e];
  if ((unsigned)d >= NN) return;
  atomicAdd(&deg[d], 1);
}

__global__ __launch_bounds__(1024)
void k_scan(const int* __restrict__ deg, int* __restrict__ offs, int* __restrict__ cursor) {
  __shared__ int part[1024];
  const int t = threadIdx.x;
  const int CH = (NN + 1023) / 1024;  // 20
  const int base = t * CH;
  int s = 0;
  for (int i = 0; i < CH; ++i) { int idx = base + i; if (idx < NN) s += deg[idx]; }
  part[t] = s;
  __syncthreads();
  for (int off = 1; off < 1024; off <<= 1) {
    int v = (t >= off) ? part[t - off] : 0;
    __syncthreads();
    part[t] += v;
    __syncthreads();
  }
  int run = (t == 0) ? 0 : part[t - 1];  // exclusive prefix
  for (int i = 0; i < CH; ++i) {
    int idx = base + i;
    if (idx < NN) { offs[idx] = run; cursor[idx] = run; run += deg[idx]; }
  }
}

__global__ void k_fill(const int* __restrict__ ei, const int* __restrict__ flag,
                       int* __restrict__ cursor, int* __restrict__ csr) {
  int e = blockIdx.x * blockDim.x + threadIdx.x;
  if (e >= NE) return;
  int is64 = *flag;
  int s, d;
  if (is64) { s = ei[2 * e]; d = ei[2 * (NE + e)]; }
  else      { s = ei[e];     d = ei[NE + e]; }
  if ((unsigned)s >= NN || (unsigned)d >= NN) return;
  int pos = atomicAdd(&cursor[d], 1);
  csr[pos] = s;
}

__global__ void k_f32_to_bf16(const float4* __restrict__ src, uint2* __restrict__ dst, int n4) {
  int i = blockIdx.x * blockDim.x + threadIdx.x;
  int stride = gridDim.x * blockDim.x;
  for (; i < n4; i += stride) {
    float4 v = src[i];
    uint2 o;
    o.x = (unsigned)f2bf(v.x) | ((unsigned)f2bf(v.y) << 16);
    o.y = (unsigned)f2bf(v.z) | ((unsigned)f2bf(v.w) << 16);
    dst[i] = o;
  }
}

// ---------------- fused gather: hb = bf16(x_i + sum bf16(x_j)) ----------------
// self row read exact f32; neighbor rows read as bf16 (halves gather traffic),
// accumulated in f32. One wave per node; lane owns 8 contiguous cols (16B).
__global__ __launch_bounds__(256)
void k_gather2(const float4* __restrict__ x4, const uint4* __restrict__ xb4,
               const int* __restrict__ offs, const int* __restrict__ deg,
               const int* __restrict__ csr, uint4* __restrict__ hb4) {
  const int wid = blockIdx.x * (blockDim.x >> 6) + (threadIdx.x >> 6);
  if (wid >= NN) return;
  const int lane = threadIdx.x & 63;
  float4 s0 = x4[(long long)wid * 128 + lane * 2];
  float4 s1 = x4[(long long)wid * 128 + lane * 2 + 1];
  float a0 = s0.x, a1 = s0.y, a2 = s0.z, a3 = s0.w;
  float a4 = s1.x, a5 = s1.y, a6 = s1.z, a7 = s1.w;
  const int beg = offs[wid];
  const int dc  = deg[wid];
  for (int j = 0; j < dc; ++j) {
    int s = csr[beg + j];
    uint4 v = xb4[(long long)s * 64 + lane];
    a0 += __uint_as_float(v.x << 16); a1 += __uint_as_float(v.x & 0xffff0000u);
    a2 += __uint_as_float(v.y << 16); a3 += __uint_as_float(v.y & 0xffff0000u);
    a4 += __uint_as_float(v.z << 16); a5 += __uint_as_float(v.z & 0xffff0000u);
    a6 += __uint_as_float(v.w << 16); a7 += __uint_as_float(v.w & 0xffff0000u);
  }
  uint4 o;
  o.x = (unsigned)f2bf(a0) | ((unsigned)f2bf(a1) << 16);
  o.y = (unsigned)f2bf(a2) | ((unsigned)f2bf(a3) << 16);
  o.z = (unsigned)f2bf(a4) | ((unsigned)f2bf(a5) << 16);
  o.w = (unsigned)f2bf(a6) | ((unsigned)f2bf(a7) << 16);
  hb4[(long long)wid * 64 + lane] = o;
}

// =================== 256x256 8-phase bf16 GEMM (R5 structure) ===================
// C[M,N] = A[M,K] * B[N,K]^T + bias.  BK=64, 512 thr = 8 waves (2Mx4N),
// per-wave 128x64. LDS 128KB = 2 K-tile buffers. 8 phases / 2 K-tiles per iter;
// counted vmcnt(2) at P4/P8 only. seg-swizzle phys_seg = seg ^ (row&7),
// both-sides (pre-swizzled global src + swizzled ds_read) -> 0 conflicts (R5).
// R8 change vs R5: NO full lgkmcnt(0) drain after the opening barrier —
// compiler inserts partial lgkmcnt before each MFMA use, so read latency
// hides under the barrier wait + early MFMAs. sched_barrier(0) before every
// closing barrier pins reads+uses inside their phase (WAR safety).

#define SBAR  __builtin_amdgcn_s_barrier()
#define SCHB  __builtin_amdgcn_sched_barrier(0)
#define VMC(n) asm volatile("s_waitcnt vmcnt(" #n ")" ::: "memory")
#define PRIO1 __builtin_amdgcn_s_setprio(1)
#define PRIO0 __builtin_amdgcn_s_setprio(0)

#define READ_A(qm, bufc) \
  _Pragma("unroll") for (int m_ = 0; m_ < 4; ++m_) { \
    const char* p_ = (bufc) + aOff + (qm) * 8192 + m_ * 2048; \
    aF[m_][0] = *(const bf16x8*)(p_ + sg0); \
    aF[m_][1] = *(const bf16x8*)(p_ + sg1); \
  }

#define READ_B(qn, bufc, DST) \
  _Pragma("unroll") for (int n_ = 0; n_ < 2; ++n_) { \
    const char* p_ = (bufc) + 32768 + bOff + (qn) * 4096 + n_ * 2048; \
    DST[n_][0] = *(const bf16x8*)(p_ + sg0); \
    DST[n_][1] = *(const bf16x8*)(p_ + sg1); \
  }

#define MFMA_Q(qm, qn, BQ) \
  _Pragma("unroll") for (int m_ = 0; m_ < 4; ++m_) \
    _Pragma("unroll") for (int n_ = 0; n_ < 2; ++n_) { \
      acc[(qm)*4+m_][(qn)*2+n_] = __builtin_amdgcn_mfma_f32_16x16x32_bf16( \
          aF[m_][0], BQ[n_][0], acc[(qm)*4+m_][(qn)*2+n_], 0, 0, 0); \
      acc[(qm)*4+m_][(qn)*2+n_] = __builtin_amdgcn_mfma_f32_16x16x32_bf16( \
          aF[m_][1], BQ[n_][1], acc[(qm)*4+m_][(qn)*2+n_], 0, 0, 0); \
    }

#define STAGE_A(bufc, kt, ha) \
  _Pragma("unroll") for (int j_ = 0; j_ < 2; ++j_) { \
    int rl_ = (ha) * 128 + (w * 2 + j_) * 8 + stSub; \
    int gr_ = aRow0 + rl_; if (gr_ > Mm1) gr_ = Mm1; \
    __builtin_amdgcn_global_load_lds( \
      (const __attribute__((address_space(1))) void*)(A + (long long)gr_ * K + (kt) * 64 + stSeg8), \
      (__attribute__((address_space(3))) void*)((bufc) + (ha) * 16384 + (w * 2 + j_) * 1024), \
      16, 0, 0); \
  }

#define STAGE_B(bufc, kt, ha) \
  _Pragma("unroll") for (int j_ = 0; j_ < 2; ++j_) { \
    int rl_ = (ha) * 128 + (w * 2 + j_) * 8 + stSub; \
    int gr_ = bRow0 + rl_; \
    __builtin_amdgcn_global_load_lds( \
      (const __attribute__((address_space(1))) void*)(B + (long long)gr_ * K + (kt) * 64 + stSeg8), \
      (__attribute__((address_space(3))) void*)((bufc) + 32768 + (ha) * 16384 + (w * 2 + j_) * 1024), \
      16, 0, 0); \
  }

template<bool OUT_BF16>
__global__ __launch_bounds__(512, 2)
void k_gemm256(const unsigned short* __restrict__ A,   // [M,K] bf16
               const unsigned short* __restrict__ B,   // [N,K] bf16
               const float* __restrict__ bias,         // [N]
               void* __restrict__ C,                   // [M,N] f32 or bf16
               int M, int N, int K)
{
  __shared__ __align__(16) char lds[131072];   // 2 x (A 32KB + B 32KB)

  const int tid  = threadIdx.x;
  const int lane = tid & 63;
  const int w    = tid >> 6;       // 0..7
  const int wr   = w >> 2;         // 0..1  (M)
  const int wc   = w & 3;          // 0..3  (N)

  // grid mapping: bn-chunk per XCD if possible, else m204 bijective swizzle
  const int nwg  = gridDim.x * gridDim.y;
  const int orig = blockIdx.y * gridDim.x + blockIdx.x;
  int bn, bm;
  if ((gridDim.x & 7) == 0 && (nwg & 7) == 0) {
    const int xcd = orig & 7;
    const int j   = orig >> 3;
    const int chunk = gridDim.x >> 3;
    bn = xcd * chunk + (j % chunk);
    bm = j / chunk;
  } else {
    const int q = nwg >> 3, r = nwg & 7;
    const int xcd = orig & 7, land = orig >> 3;
    const int nid = (xcd < r ? xcd * (q + 1) : r * (q + 1) + (xcd - r) * q) + land;
    bn = nid % gridDim.x;
    bm = nid / gridDim.x;
  }

  // per-lane constants
  const int lm = lane & 15;
  const int lk = lane >> 4;                       // 0..3
  const int l7 = lane & 7;
  const int sg0 = ((lk    ) ^ l7) * 16;           // swizzled seg byte off, ks=0
  const int sg1 = ((lk + 4) ^ l7) * 16;           // ks=1
  const int aOff = (wr * 128 + lm) * 128;         // A read base (bytes)
  const int bOff = (wc * 64  + lm) * 128;         // B read base (bytes)
  const int stSub  = lane >> 3;                   // 0..7
  const int stSeg8 = ((lane & 7) ^ stSub) * 8;    // pre-swizzled source seg (elems)
  const int aRow0 = bm * 256;
  const int bRow0 = bn * 256;
  const int Mm1 = M - 1;

  char* lb0 = (char*)lds;            // even K-tiles
  char* lb1 = (char*)lds + 65536;    // odd K-tiles

  f32x4 acc[8][4] = {};
  bf16x8 aF[4][2], bF0[2][2], bF1[2][2];

  const int nkt = K >> 6;            // 64-wide K tiles (even count for 512/4352)
  const int nit = nkt >> 1;

  // prologue: tile0 full + tile1.A0
  STAGE_A(lb0, 0, 0); STAGE_A(lb0, 0, 1); STAGE_B(lb0, 0, 0); STAGE_B(lb0, 0, 1);
  STAGE_A(lb1, 1, 0);
  VMC(2);
  SBAR;

  for (int i = 0; i < nit; ++i) {
    const int ktO = 2 * i + 1;
    int ktE2 = 2 * i + 2; if (ktE2 >= nkt) ktE2 = nkt - 1;  // clamped junk on last iter
    int ktO2 = 2 * i + 3; if (ktO2 >= nkt) ktO2 = nkt - 1;
    // P1: tile E quad(0,0)
    READ_A(0, lb0); READ_B(0, lb0, bF0);
    STAGE_A(lb1, ktO, 1);
    SBAR; PRIO1; MFMA_Q(0, 0, bF0); PRIO0; SCHB; SBAR;
    // P2: quad(0,1)
    READ_B(1, lb0, bF1);
    STAGE_B(lb1, ktO, 0);
    SBAR; PRIO1; MFMA_Q(0, 1, bF1); PRIO0; SCHB; SBAR;
    // P3: quad(1,1)
    READ_A(1, lb0);
    STAGE_B(lb1, ktO, 1);
    SBAR; PRIO1; MFMA_Q(1, 1, bF1); PRIO0; SCHB; SBAR;
    // P4: quad(1,0)  (no new reads)
    STAGE_A(lb0, ktE2, 0);
    SBAR; PRIO1; MFMA_Q(1, 0, bF0); PRIO0; SCHB; VMC(2); SBAR;
    // P5: tile O quad(0,0)
    READ_A(0, lb1); READ_B(0, lb1, bF0);
    STAGE_A(lb0, ktE2, 1);
    SBAR; PRIO1; MFMA_Q(0, 0, bF0); PRIO0; SCHB; SBAR;
    // P6: quad(0,1)
    READ_B(1, lb1, bF1);
    STAGE_B(lb0, ktE2, 0);
    SBAR; PRIO1; MFMA_Q(0, 1, bF1); PRIO0; SCHB; SBAR;
    // P7: quad(1,1)
    READ_A(1, lb1);
    STAGE_B(lb0, ktE2, 1);
    SBAR; PRIO1; MFMA_Q(1, 1, bF1); PRIO0; SCHB; SBAR;
    // P8: quad(1,0)
    STAGE_A(lb1, ktO2, 0);
    SBAR; PRIO1; MFMA_Q(1, 0, bF0); PRIO0; SCHB; VMC(2); SBAR;
  }

  // epilogue: C[row, col] = acc + bias
#pragma unroll
  for (int in = 0; in < 4; ++in) {
    const int col = bn * 256 + wc * 64 + in * 16 + lm;
    const float bv = bias[col];
#pragma unroll
    for (int im = 0; im < 8; ++im) {
      const int row0 = bm * 256 + wr * 128 + im * 16 + lk * 4;
#pragma unroll
      for (int jj = 0; jj < 4; ++jj) {
        const int row = row0 + jj;
        if (row < M) {
          const float v = acc[im][in][jj] + bv;
          if (OUT_BF16)
            __builtin_nontemporal_store(f2bf(v), &((unsigned short*)C)[(long long)row * N + col]);
          else
            __builtin_nontemporal_store(v, &((float*)C)[(long long)row * N + col]);
        }
      }
    }
  }
}

extern "C" void kernel_launch(void* const* d_in, const int* in_sizes, int n_in,
                              void* d_out, int out_size, void* d_ws, size_t ws_size,
                              hipStream_t stream) {
  const float* x  = (const float*)d_in[0];
  const int*   ei = (const int*)d_in[1];      // int32 or int64 — detected on device
  const float* W1 = (const float*)d_in[2];
  const float* b1 = (const float*)d_in[3];
  const float* W2 = (const float*)d_in[4];
  const float* b2 = (const float*)d_in[5];
  float* out = (float*)d_out;
  char* ws = (char*)d_ws;

  // workspace layout (bytes, 16B-aligned)
  int* flag            = (int*)(ws + 0);                    // 256
  int* deg             = (int*)(ws + 256);                  // 80,000
  int* offs            = (int*)(ws + 80256);                // 80,000
  int* cursor          = (int*)(ws + 160256);               // 80,000
  int* csr             = (int*)(ws + 240256);               // 2,560,000
  unsigned short* xb   = (unsigned short*)(ws + 2800256);   // 20,480,000
  unsigned short* hb   = (unsigned short*)(ws + 23280256);  // 20,480,000
  unsigned short* w1b  = (unsigned short*)(ws + 43760256);  //  4,456,448
  unsigned short* w2b  = (unsigned short*)(ws + 48216704);  // 71,303,168
  const size_t h1_off  = 119519872;
  if (ws_size < h1_off + (size_t)256 * MID * 2) return;
  unsigned short* h1b  = (unsigned short*)(ws + h1_off);

  long long rem = (long long)ws_size - (long long)h1_off;
  int max_rows = (int)(rem / ((long long)MID * 2));
  max_rows = (max_rows / 256) * 256;
  if (max_rows > 20224) max_rows = 20224;

  // 0) detect edge_index width
  k_detect64<<<1, 256, 0, stream>>>(ei, flag);

  // 1) CSR build
  k_zero_i32<<<(NN + 255) / 256, 256, 0, stream>>>(deg, NN);
  k_count<<<(NE + 255) / 256, 256, 0, stream>>>(ei, flag, deg);
  k_scan<<<1, 1024, 0, stream>>>(deg, offs, cursor);
  k_fill<<<(NE + 255) / 256, 256, 0, stream>>>(ei, flag, cursor, csr);

  // 2) conversions to bf16 (x first: gather depends on it)
  k_f32_to_bf16<<<2048, 256, 0, stream>>>((const float4*)x,  (uint2*)xb,  NN * HID / 4);
  k_f32_to_bf16<<<1024, 256, 0, stream>>>((const float4*)W1, (uint2*)w1b, MID * HID / 4);
  k_f32_to_bf16<<<2048, 256, 0, stream>>>((const float4*)W2, (uint2*)w2b, VOC * MID / 4);

  // 3) fused gather: hb = bf16(x_i + sum_j bf16(x_j))
  k_gather2<<<(NN + 3) / 4, 256, 0, stream>>>((const float4*)x, (const uint4*)xb,
                                              offs, deg, csr, (uint4*)hb);

  // 4+5) chunked GEMM1 -> GEMM2 over M (usually a single chunk)
  for (int r0 = 0; r0 < NN; r0 += max_rows) {
    int mrows = (NN - r0 < max_rows) ? (NN - r0) : max_rows;
    dim3 g1(MID / 256, (mrows + 255) / 256);
    k_gemm256<true><<<g1, 512, 0, stream>>>(hb + (size_t)r0 * HID, w1b, b1,
                                            (void*)h1b, mrows, MID, HID);
    dim3 g2(VOC / 256, (mrows + 255) / 256);
    k_gemm256<false><<<g2, 512, 0, stream>>>(h1b, w2b, b2,
                                             (void*)(out + (size_t)r0 * VOC), mrows, VOC, MID);
  }
}